// Round 9
// baseline (196.470 us; speedup 1.0000x reference)
//
#include <hip/hip_runtime.h>

#define D_DIM 1024
#define NROWS 8192

typedef float f32x4 __attribute__((ext_vector_type(4)));
typedef int   i32x4 __attribute__((ext_vector_type(4)));
typedef int   i32x8 __attribute__((ext_vector_type(8)));

typedef const __attribute__((address_space(1))) void* gaddr_t;
typedef __attribute__((address_space(3))) void* laddr_t;

__device__ __forceinline__ void load16_to_lds(const void* g, void* l) {
    __builtin_amdgcn_global_load_lds((gaddr_t)g, (laddr_t)l, 16, 0, 0);
}

// ---- kernel 1: fp32 row-normalize -> fp8 e4m3, one WAVE per row (no barriers).
// K is PERMUTED within each 128-element block (identically for A and B — dot
// products are K-permutation-invariant): orig k = 32s+8f+b (s=step 0..3,
// f=lane quarter 0..3, b=0..7) stored at byte (f + 4*(s>>1))*16 + (s&1)*8 + b.
// Lane l owns dest 16-B chunk at byte 16*l: chunk l = {blk=l>>3, q=(l>>2)&1,
// f=l&3} holds orig elements [base,base+8) and [base+32,base+40) with
// base = 128*blk + 64*q + 8*f. ONE coalesced 16-B store/lane; 4 float4
// loads/lane cover the row exactly once.
// Also zeroes the encoded-max array and d_out (poisoned 0xAA every launch).
__global__ __launch_bounds__(256) void normalize_rows(const float* __restrict__ ex,
                                                      const float* __restrict__ ey,
                                                      unsigned char* __restrict__ Aq,
                                                      unsigned char* __restrict__ Bq,
                                                      int* __restrict__ maxenc,
                                                      float* __restrict__ out) {
    const int wave = threadIdx.x >> 6, lane = threadIdx.x & 63;
    const int r = blockIdx.x * 4 + wave;
    if (lane == 0) maxenc[r] = 0;   // 0 < int-encoding of any (cosine+2.0) > 0
    if (blockIdx.x == 0 && threadIdx.x < 2) out[threadIdx.x] = 0.0f;

    const float* src;
    unsigned char* dst;
    if (r < NROWS) { src = ex + (size_t)r * D_DIM;           dst = Aq + (size_t)r * D_DIM; }
    else           { src = ey + (size_t)(r - NROWS) * D_DIM; dst = Bq + (size_t)(r - NROWS) * D_DIM; }

    const int base4 = (lane >> 3) * 32 + ((lane >> 2) & 1) * 16 + (lane & 3) * 2; // float4 idx of base
    float4 va = ((const float4*)src)[base4];       // elements base .. base+3
    float4 vb = ((const float4*)src)[base4 + 1];   // base+4 .. base+7
    float4 vc = ((const float4*)src)[base4 + 8];   // base+32 .. base+35
    float4 vd = ((const float4*)src)[base4 + 9];   // base+36 .. base+39

    float ss = va.x * va.x + va.y * va.y + va.z * va.z + va.w * va.w
             + vb.x * vb.x + vb.y * vb.y + vb.z * vb.z + vb.w * vb.w
             + vc.x * vc.x + vc.y * vc.y + vc.z * vc.z + vc.w * vc.w
             + vd.x * vd.x + vd.y * vd.y + vd.z * vd.z + vd.w * vd.w;
    #pragma unroll
    for (int off = 32; off; off >>= 1) ss += __shfl_xor(ss, off, 64);
    float sc = 1.0f / fmaxf(sqrtf(ss), 1e-8f);

    i32x4 o;   // v_cvt_pk_fp8_f32: RNE, saturating; |x| <= ~0.3, no overflow
    int w;
    w = __builtin_amdgcn_cvt_pk_fp8_f32(va.x * sc, va.y * sc, 0, false);
    o[0] = __builtin_amdgcn_cvt_pk_fp8_f32(va.z * sc, va.w * sc, w, true);
    w = __builtin_amdgcn_cvt_pk_fp8_f32(vb.x * sc, vb.y * sc, 0, false);
    o[1] = __builtin_amdgcn_cvt_pk_fp8_f32(vb.z * sc, vb.w * sc, w, true);
    w = __builtin_amdgcn_cvt_pk_fp8_f32(vc.x * sc, vc.y * sc, 0, false);
    o[2] = __builtin_amdgcn_cvt_pk_fp8_f32(vc.z * sc, vc.w * sc, w, true);
    w = __builtin_amdgcn_cvt_pk_fp8_f32(vd.x * sc, vd.y * sc, 0, false);
    o[3] = __builtin_amdgcn_cvt_pk_fp8_f32(vd.z * sc, vd.w * sc, w, true);
    ((i32x4*)dst)[lane] = o;
}

// ---- kernel 2: 128x128-tile fp8 MFMA GEMM (C = A . B^T) with fused row/col max.
// MX-scaled v_mfma_scale_f32_16x16x128_f8f6f4, unit scales (E8M0 0x7F = 2^0)
// = exact fp8 math at ~2x non-scaled rate. BK=128, zero bank conflicts (16-B
// XOR swizzle + K-permutation), XCD-aware 8x8 supertile block swizzle,
// #pragma unroll 1 + incremental pointers (any kt-unroll balloons addressing
// to ~244 VGPR and spills under caps — R11/12/13/15).
// R16/R18 (single 32 KB buffer, __syncthreads x2): 85 us, MfmaUtil 33%,
// no pipe saturated (LDS ~48%, HBM 36%) -> serialization-bound: every iter
// pays the vmcnt(0) stage-drain (~900 cyc) inside the barrier.
// R17 (dbuf + __syncthreads): REGRESSED 114 us — syncthreads drains vmcnt(0),
// prefetch nullified, and 64 KB LDS cost a resident block.
// R19: dbuf + COUNTED vmcnt + raw s_barrier (guide T3/T4 minimal form):
//   iter tt: issue 8 loads -> buf[tt+1 & 1]; s_waitcnt vmcnt(8) (drains ONLY
//   the previous tile's 8 loads, leaves the new 8 in flight ACROSS the
//   barrier); s_barrier; compute buf[tt&1]; s_barrier.
// Correctness: each wave drains its OWN prior-8 before the barrier; after the
// barrier all waves have -> buffer fully written. End-of-compute barrier
// protects buf[cur] before iter tt+2 overwrites it. sched_barrier(0) fences
// prevent ds_read/load hoisting across the raw barriers (rule #18 hazard).
// Cost: 64 KB LDS -> 2 blocks/CU; win: stage latency fully off the serial
// path. Floors: LDS-issue 41 us, HBM 38, MFMA 29.5 -> expect 55-70 us.
__global__ __launch_bounds__(256, 2) void gemm_max(const unsigned char* __restrict__ A,
                                                   const unsigned char* __restrict__ B,
                                                   int* __restrict__ rowmax,
                                                   int* __restrict__ colmax) {
    __shared__ __align__(16) unsigned char Alds[2][128 * 128];   // 32 KB
    __shared__ __align__(16) unsigned char Blds[2][128 * 128];   // 32 KB

    const int bid = blockIdx.x;
    const int sgr = bid >> 6;
    const int bm  = ((sgr & 7) << 3) | ((bid >> 3) & 7);
    const int bn  = ((sgr >> 3) << 3) | (bid & 7);
    const int rowb = bm * 128;
    const int colb = bn * 128;

    const int t    = threadIdx.x;
    const int lane = t & 63;
    const int wave = t >> 6;
    const int wm = (wave & 1) * 64;       // wave row offset within tile
    const int wn = (wave >> 1) * 64;      // wave col offset within tile
    const int fr = lane & 15;             // fragment row/col index
    const int fq = lane >> 4;             // quarter: k-chunk index
    const int pos1 = (fq ^ (fr & 7)) * 16;   // swizzled LDS pos of chunk fq

    // staging: thread t stages LDS (row t>>3, pos t&7) <- global chunk (t&7)^(row&7)
    const int srow = t >> 3;
    const int scol = ((t ^ (t >> 3)) & 7) * 16;

    const unsigned char* ag = A + (size_t)(rowb + srow) * D_DIM + scol;
    const unsigned char* bg = B + (size_t)(colb + srow) * D_DIM + scol;

    f32x4 acc[4][4] = {};

    // stage tile tt into the given buffers, advance pointers
#define STAGE(Abuf, Bbuf)                                                        \
    do {                                                                         \
        _Pragma("unroll")                                                        \
        for (int i = 0; i < 4; ++i)                                              \
            load16_to_lds(ag + (size_t)i * 32 * D_DIM,                           \
                          (char*)(Abuf) + i * 4096 + wave * 1024);               \
        _Pragma("unroll")                                                        \
        for (int i = 0; i < 4; ++i)                                              \
            load16_to_lds(bg + (size_t)i * 32 * D_DIM,                           \
                          (char*)(Bbuf) + i * 4096 + wave * 1024);               \
        ag += 128; bg += 128;                                                    \
    } while (0)

    // one K-tile of MFMA work from the given buffers
#define COMPUTE(Ac, Bc)                                                          \
    do {                                                                         \
        i32x8 af[4];                                                             \
        _Pragma("unroll")                                                        \
        for (int i = 0; i < 4; ++i) {                                            \
            i32x4 lo = *(const i32x4*)((Ac) + (wm + i * 16 + fr) * 128 + pos1);  \
            i32x4 hi = *(const i32x4*)((Ac) + (wm + i * 16 + fr) * 128 + (pos1 ^ 64)); \
            af[i] = __builtin_shufflevector(lo, hi, 0, 1, 2, 3, 4, 5, 6, 7);     \
        }                                                                        \
        _Pragma("unroll")                                                        \
        for (int j = 0; j < 4; ++j) {                                            \
            i32x4 lo = *(const i32x4*)((Bc) + (wn + j * 16 + fr) * 128 + pos1);  \
            i32x4 hi = *(const i32x4*)((Bc) + (wn + j * 16 + fr) * 128 + (pos1 ^ 64)); \
            i32x8 bf = __builtin_shufflevector(lo, hi, 0, 1, 2, 3, 4, 5, 6, 7);  \
            _Pragma("unroll")                                                    \
            for (int i = 0; i < 4; ++i)                                          \
                acc[i][j] = __builtin_amdgcn_mfma_scale_f32_16x16x128_f8f6f4(    \
                    af[i], bf, acc[i][j],                                        \
                    0, 0, 0, 0x7F7F7F7F, 0, 0x7F7F7F7F);                         \
        }                                                                        \
    } while (0)

    // prologue: stage tile 0 into buffer 0
    STAGE(Alds[0], Blds[0]);

    #pragma unroll 1
    for (int tt = 0; tt < 7; ++tt) {
        const unsigned char* Ac = Alds[tt & 1];
        const unsigned char* Bc = Blds[tt & 1];
        // prefetch tile tt+1 into the other buffer (its last readers passed
        // the end-barrier of iter tt-1)
        STAGE(Alds[(tt + 1) & 1], Blds[(tt + 1) & 1]);
        // drain ONLY the previous tile's 8 loads; the 8 just issued stay in
        // flight across the barrier (T4: never vmcnt(0) in the main loop)
        asm volatile("s_waitcnt vmcnt(8)" ::: "memory");
        __builtin_amdgcn_s_barrier();          // all waves' buf[tt] loads done
        __builtin_amdgcn_sched_barrier(0);     // no ds_read hoists above barrier
        COMPUTE(Ac, Bc);
        __builtin_amdgcn_sched_barrier(0);
        __builtin_amdgcn_s_barrier();          // all waves done reading buf[tt]
    }
    // epilogue tile 7: drain its loads fully, no further prefetch
    asm volatile("s_waitcnt vmcnt(0)" ::: "memory");
    __builtin_amdgcn_s_barrier();
    __builtin_amdgcn_sched_barrier(0);
    COMPUTE(Alds[1], Blds[1]);

#undef STAGE
#undef COMPUTE

    // ---- epilogue: fused max reductions.
    // C/D layout (shape-determined, m89-verified): col = lane&15, row = fq*4 + reg.
    const float SH = 2.0f;   // cosine >= -1 -> v+2 > 0 -> int-ordered float bits

    #pragma unroll
    for (int i = 0; i < 4; ++i) {
        #pragma unroll
        for (int r = 0; r < 4; ++r) {
            float m = fmaxf(fmaxf(acc[i][0][r], acc[i][1][r]),
                            fmaxf(acc[i][2][r], acc[i][3][r]));
            m = fmaxf(m, __shfl_xor(m, 1, 64));   // reduce over the 16 lanes sharing fq
            m = fmaxf(m, __shfl_xor(m, 2, 64));
            m = fmaxf(m, __shfl_xor(m, 4, 64));
            m = fmaxf(m, __shfl_xor(m, 8, 64));
            if (fr == 0) {
                int row = rowb + wm + i * 16 + fq * 4 + r;
                atomicMax(&rowmax[row], __float_as_int(m + SH));
            }
        }
    }
    #pragma unroll
    for (int j = 0; j < 4; ++j) {
        float m = -1e30f;
        #pragma unroll
        for (int i = 0; i < 4; ++i)
            #pragma unroll
            for (int r = 0; r < 4; ++r)
                m = fmaxf(m, acc[i][j][r]);
        m = fmaxf(m, __shfl_xor(m, 16, 64));      // reduce over the 4 quarters
        m = fmaxf(m, __shfl_xor(m, 32, 64));
        if (fq == 0) {
            int col = colb + wn + j * 16 + fr;
            atomicMax(&colmax[col], __float_as_int(m + SH));
        }
    }
}

// ---- kernel 3: decode maxes, log-prob, partial-sum, atomicAdd into out.
// 64 blocks x 256 threads over the contiguous [rowmax | colmax] array; each
// block's 256 entries lie entirely in one half. out zeroed by normalize_rows.
__global__ __launch_bounds__(256) void finalize(const int* __restrict__ maxenc,
                                                float* __restrict__ out) {
    int idx = blockIdx.x * 256 + threadIdx.x;
    float v = __int_as_float(maxenc[idx]) - 2.0f;
    float z = (v - 1.0f) * (1.0f / 0.3f);
    float s = -0.5f * z * z + 0.2850342711212634f;   // -(log(0.3)+0.5*log(2*pi))
    #pragma unroll
    for (int off = 32; off; off >>= 1) s += __shfl_xor(s, off, 64);
    __shared__ float wsum[4];
    if ((threadIdx.x & 63) == 0) wsum[threadIdx.x >> 6] = s;
    __syncthreads();
    if (threadIdx.x == 0)
        atomicAdd(&out[idx >= NROWS ? 1 : 0], wsum[0] + wsum[1] + wsum[2] + wsum[3]);
}

extern "C" void kernel_launch(void* const* d_in, const int* in_sizes, int n_in,
                              void* d_out, int out_size, void* d_ws, size_t ws_size,
                              hipStream_t stream) {
    const float* ex = (const float*)d_in[0];
    const float* ey = (const float*)d_in[1];
    float* out = (float*)d_out;

    char* ws = (char*)d_ws;
    unsigned char* Aq = (unsigned char*)ws;                                   // 8 MB
    unsigned char* Bq = (unsigned char*)(ws + (size_t)NROWS * D_DIM);         // 8 MB
    int* rowmax = (int*)(ws + (size_t)2 * NROWS * D_DIM);                     // 32 KB
    int* colmax = rowmax + NROWS;                                             // 32 KB

    normalize_rows<<<(2 * NROWS) / 4, 256, 0, stream>>>(ex, ey, Aq, Bq, rowmax, out);
    gemm_max<<<64 * 64, 256, 0, stream>>>(Aq, Bq, rowmax, colmax);
    finalize<<<64, 256, 0, stream>>>(rowmax, out);
}